// Round 18
// baseline (3743.539 us; speedup 1.0000x reference)
//
#include <hip/hip_runtime.h>

// ---------------------------------------------------------------------------
// TranslatorEncoderRNN: bidirectional masked LSTM encoder.
// B=64, T=512, E=512, H=512 (per dir), V=32000, PAD=0.
// Outputs (flat): output (B,T,1024) f32 | ht (B,1024) | ct (B,1024) | mask (B,T)
//
// R18: R16 (green, 3498us) + gx de-burst ONLY (nt rotation + sleep pacing,
// perf-only, no asm loads involved). R17's poll micro-pipeline is DEAD:
// r[8]+rn[8] = 16 live asm-load dest regs -> spill (1.1118), confirming the
// sharpened rule below.
// CONSTRAINTS (empirical R3-R17):
//   (a) unconditional batch of <=8 ld_co16 + vmcnt(0) + sched_barrier(0); or
//   (b) fused {load; waitcnt} single asm block.
//   <=8 asm-load DEST REGS LIVE AT ANY POINT (not just at the drain) —
//     R17's 16-live pipeline spilled (1.1118), like R3/R4/R5/R7.
//   NEVER asm loads under divergent per-lane branches (NaN signature).
//   gx must keep >=64 parallel blocks + LDS-staged B (R13/R15 regressions).
//   lstm_recur stays 256 thr (512-thr remap failed unexplained, R12).
// ---------------------------------------------------------------------------

#define Bn 64
#define Tn 512
#define NWG 64             // recurrence blocks (32 per direction)
#define TC 32              // chunk length
#define NCH 16             // chunks

#define OUT_HT  33554432u  // B*T*2H
#define OUT_CT  33619968u
#define OUT_MSK 33685504u

// ws layout (bytes) — total 42,991,616 (proven green R14/R16)
#define WS_WCAT 0ull           // Wcat bf16 [2][2048][1024]   =  8388608
#define WS_GX0  8388608ull     // gxb buf0 bf16 [2][32][64][2048] = 16777216
#define WS_GX1  25165824ull    // gxb buf1 (same)             = 16777216
#define WS_REC  41943040ull    // rec [2][2][8192]x16B        =   524288
#define WS_HST  42467328ull    // hstate f32 [2][64][512]     =   262144
#define WS_CST  42729472ull    // cstate f32 [2][64][512]     =   262144

typedef __bf16 v8bf __attribute__((ext_vector_type(8)));
typedef float  v4f  __attribute__((ext_vector_type(4)));
typedef unsigned v4u __attribute__((ext_vector_type(4)));
typedef unsigned v2u __attribute__((ext_vector_type(2)));

__device__ __forceinline__ unsigned short f2bf(float f) {
    unsigned u = __float_as_uint(f);
    u = (u + 0x7FFFu + ((u >> 16) & 1u)) >> 16;   // round-to-nearest-even
    return (unsigned short)u;
}

__device__ __forceinline__ void bf2x(unsigned u, float& lo, float& hi) {
    lo = __uint_as_float(u << 16);
    hi = __uint_as_float(u & 0xffff0000u);
}

__device__ __forceinline__ v8bf ldfrag(const unsigned short* p) {
    return *reinterpret_cast<const v8bf*>(p);
}

// coherent 16B load, ASYNC issue — pattern (a) only
__device__ __forceinline__ v4u ld_co16(const void* p) {
    v4u r;
    asm volatile("global_load_dwordx4 %0, %1, off sc0 sc1" : "=v"(r) : "v"(p));
    return r;
}

__device__ __forceinline__ float fsig(float x) {
    return 1.0f / (1.0f + __expf(-x));
}
__device__ __forceinline__ float ftanh(float x) {
    x = fminf(fmaxf(x, -15.0f), 15.0f);
    float e = __expf(2.0f * x);
    return (e - 1.0f) / (e + 1.0f);
}

// --------------------------- prep kernels ----------------------------------

__global__ void k_weights(const float* __restrict__ Wih_f, const float* __restrict__ Whh_f,
                          const float* __restrict__ Wih_b, const float* __restrict__ Whh_b,
                          unsigned short* __restrict__ Wcat) {
    int idx = blockIdx.x * 256 + threadIdx.x;       // one per 4 elements
    if (idx >= 2 * 2048 * 256) return;
    int k4 = idx & 255;
    int n  = (idx >> 8) & 2047;
    int d  = idx >> 19;
    int k  = k4 * 4;
    const float* src;
    if (k < 512) src = (d ? Wih_b : Wih_f) + (size_t)n * 512 + k;
    else         src = (d ? Whh_b : Whh_f) + (size_t)n * 512 + (k - 512);
    float4 v = *(const float4*)src;
    unsigned short o[4] = { f2bf(v.x), f2bf(v.y), f2bf(v.z), f2bf(v.w) };
    *(ushort4*)(Wcat + (size_t)idx * 4) = *(const ushort4*)o;
}

// zero records (stamps) and h/c carry state
__global__ void k_zero(unsigned char* __restrict__ recb,
                       float* __restrict__ hstate, float* __restrict__ cstate) {
    int i = blockIdx.x * 256 + threadIdx.x;         // grid 256x256 = 65536
    if (i < 32768) { v4u z = {0,0,0,0}; ((v4u*)recb)[i] = z; }
    if (i < 65536) { hstate[i] = 0.0f; cstate[i] = 0.0f; }
}

__global__ void k_mask(const int* __restrict__ lengths, float* __restrict__ mask_out) {
    int i = blockIdx.x * 256 + threadIdx.x;
    if (i >= Bn * Tn) return;
    int b = i >> 9, t = i & 511;
    mask_out[i] = (t < lengths[b]) ? 1.0f : 0.0f;
}

// --------------------------- embedding gather to regs -----------------------

__device__ __forceinline__ void gather_af(
    const int* __restrict__ inputs, const float* __restrict__ table,
    int d, int s, int ab, v8bf* af, int kq)
{
    const int t   = d ? (511 - s) : s;
    const int tok = inputs[ab * 512 + t];
    if (tok != 0) {
        const float* tr = table + (size_t)tok * 512 + kq * 8;
        #pragma unroll
        for (int ks = 0; ks < 16; ++ks) {
            float4 v0 = *(const float4*)(tr + ks * 32);
            float4 v1 = *(const float4*)(tr + ks * 32 + 4);
            unsigned short o[8] = { f2bf(v0.x), f2bf(v0.y), f2bf(v0.z), f2bf(v0.w),
                                    f2bf(v1.x), f2bf(v1.y), f2bf(v1.z), f2bf(v1.w) };
            af[ks] = *(const v8bf*)o;
        }
    } else {
        v4u z = {0u, 0u, 0u, 0u};
        #pragma unroll
        for (int ks = 0; ks < 16; ++ks) af[ks] = __builtin_bit_cast(v8bf, z);
    }
}

// --------------------------- standalone k_gx (prologue, chunk 0) ------------
// Green R11 form: 256 blocks (d,slg,nt), LDS-staged B tile, 4 slots.

__global__ __launch_bounds__(256) void k_gx(
    const int* __restrict__ inputs,
    const float* __restrict__ table,
    const unsigned short* __restrict__ Wcat,
    const float* __restrict__ bih_f, const float* __restrict__ bhh_f,
    const float* __restrict__ bih_b, const float* __restrict__ bhh_b,
    unsigned short* __restrict__ gxw, int s0)
{
    __shared__ unsigned short Bs[128 * 512];        // 128 KB
    const int bi   = blockIdx.x;                    // grid 256
    const int nt   = bi >> 4;                       // stride-16 -> same XCD per (d,slg)
    const int d    = (bi >> 3) & 1;
    const int slg  = bi & 7;
    const int n0   = nt * 128;
    const int tid  = threadIdx.x;
    const int lane = tid & 63, wave = tid >> 6;
    const int l15  = lane & 15, kq = lane >> 4;

    const unsigned short* Wd = Wcat + (size_t)d * (2048 * 1024);

    #pragma unroll
    for (int i = 0; i < 32; ++i) {
        int w = i * 256 + tid;
        int r = w >> 6, c = w & 63;
        v4u tmp = *(const v4u*)(Wd + (size_t)(n0 + r) * 1024 + c * 8);
        *(v4u*)&Bs[r * 512 + ((c ^ (r & 7)) * 8)] = tmp;
    }

    const float* bih = d ? bih_b : bih_f;
    const float* bhh = d ? bhh_b : bhh_f;
    float bv[8];
    #pragma unroll
    for (int n2 = 0; n2 < 8; ++n2) {
        int n = n0 + n2 * 16 + l15;
        bv[n2] = bih[n] + bhh[n];
    }
    __syncthreads();

    const int ab   = wave * 16 + l15;
    const int brow = wave * 16 + kq * 4;

    #pragma unroll 1
    for (int q = 0; q < 4; ++q) {
        const int sl = slg * 4 + q;
        v8bf af[16];
        gather_af(inputs, table, d, s0 + sl, ab, af, kq);

        unsigned short* gbase = gxw + ((size_t)(d * TC + sl) * 64) * 2048;
        #pragma unroll
        for (int n2 = 0; n2 < 8; ++n2) {
            v4f acc = {0, 0, 0, 0};
            const int rb = n2 * 16 + l15;
            const unsigned short* bbp = Bs + rb * 512;
            const int sw = rb & 7;
            #pragma unroll
            for (int ks = 0; ks < 16; ++ks) {
                v8bf bf = *(const v8bf*)&bbp[((ks * 4 + kq) ^ sw) * 8];
                acc = __builtin_amdgcn_mfma_f32_16x16x32_bf16(af[ks], bf, acc, 0, 0, 0);
            }
            const int n = n0 + n2 * 16 + l15;
            #pragma unroll
            for (int qq = 0; qq < 4; ++qq)
                gbase[(size_t)(brow + qq) * 2048 + n] = f2bf(acc[qq] + bv[n2]);
        }
    }
}

// --------------------------- fused kernel -----------------------------------
// blocks 0..63: recurrence chunk ch (reads gxb_rd) — byte-identical R16.
// blocks 64..127: gx for chunk ch+1, one block per (d,sl): gather the slot's
// 64 token rows ONCE into regs, then 16x {stage W-tile in LDS -> 8 MFMAs},
// with per-block nt rotation + sleep pacing to de-burst L2/LLC traffic.

__global__ __launch_bounds__(256, 1) void fused(
    const unsigned short* __restrict__ Wcat,
    unsigned char* __restrict__ recb,           // [2][2][8192] x 16B
    const unsigned short* __restrict__ gxb_rd,  // chunk ch
    unsigned short* __restrict__ gxb_wr,        // chunk ch+1
    const int* __restrict__ inputs,
    const float* __restrict__ table,
    const float* __restrict__ bih_f, const float* __restrict__ bhh_f,
    const float* __restrict__ bih_b, const float* __restrict__ bhh_b,
    const int* __restrict__ lengths,
    float* __restrict__ out,
    float* __restrict__ hstate,
    float* __restrict__ cstate,
    int s0, int next_s0)
{
    __shared__ __align__(16) unsigned char smem[131072];

    const int tid = threadIdx.x;

    if (blockIdx.x >= 64) {
        // ------------------ gx path (chunk ch+1) ------------------
        if (next_s0 < 0) return;
        const int gxi = blockIdx.x - 64;            // [0,64)
        const int d   = gxi >> 5;
        const int sl  = gxi & 31;
        const int lane = tid & 63, wave = tid >> 6;
        const int l15  = lane & 15, kq = lane >> 4;
        const int ab   = wave * 16 + l15;
        const int brow = wave * 16 + kq * 4;
        unsigned short* Bs = (unsigned short*)smem;
        const unsigned short* Wd = Wcat + (size_t)d * (2048 * 1024);
        const float* bih = d ? bih_b : bih_f;
        const float* bhh = d ? bhh_b : bhh_f;

        // gather this slot's 64 token rows ONCE (64 VGPRs)
        v8bf af[16];
        gather_af(inputs, table, d, next_s0 + sl, ab, af, kq);

        unsigned short* gbase = gxb_wr + ((size_t)(d * TC + sl) * 64) * 2048;

        #pragma unroll 1
        for (int nt = 0; nt < 16; ++nt) {
            if (nt) __builtin_amdgcn_s_sleep(32);   // pace: spread traffic
            const int ntr = (nt + sl) & 15;         // rotate: de-collide Wcat tiles
            const int n0 = ntr * 128;
            // stage B tile (rows n0..n0+127, k 0..511) swizzled
            #pragma unroll
            for (int i = 0; i < 32; ++i) {
                int w2 = i * 256 + tid;
                int r = w2 >> 6, c = w2 & 63;
                v4u tmp = *(const v4u*)(Wd + (size_t)(n0 + r) * 1024 + c * 8);
                *(v4u*)&Bs[r * 512 + ((c ^ (r & 7)) * 8)] = tmp;
            }
            __syncthreads();

            #pragma unroll
            for (int n2 = 0; n2 < 8; ++n2) {
                v4f acc = {0, 0, 0, 0};
                const int rb = n2 * 16 + l15;
                const unsigned short* bbp = Bs + rb * 512;
                const int sw = rb & 7;
                #pragma unroll
                for (int ks = 0; ks < 16; ++ks) {
                    v8bf bf = *(const v8bf*)&bbp[((ks * 4 + kq) ^ sw) * 8];
                    acc = __builtin_amdgcn_mfma_f32_16x16x32_bf16(af[ks], bf, acc, 0, 0, 0);
                }
                const int n = n0 + n2 * 16 + l15;
                const float bv = bih[n] + bhh[n];
                #pragma unroll
                for (int qq = 0; qq < 4; ++qq)
                    gbase[(size_t)(brow + qq) * 2048 + n] = f2bf(acc[qq] + bv);
            }
            __syncthreads();                        // Bs reuse next nt
        }
        return;
    }

    // ------------------ recurrence path (chunk ch) — R11/R16 body -------------
    unsigned short* hA = (unsigned short*)smem;             // 65536 B
    float (*gLds)[65]  = reinterpret_cast<float(*)[65]>(smem + 65536);   // 16640 B
    float (*hS)[17]    = reinterpret_cast<float(*)[17]>(smem + 82176);   //  4352 B
    float (*cS)[17]    = reinterpret_cast<float(*)[17]>(smem + 86528);   //  4352 B
    int* lenS          = reinterpret_cast<int*>(smem + 90880);           //   256 B

    const int wg   = blockIdx.x;
    const int dir  = wg >> 5;
    const int hc0  = (wg & 31) * 16;
    const int lane = tid & 63;
    const int wave = tid >> 6;
    const int wm   = wave >> 1, wn = wave & 1;
    const int l15  = lane & 15, kq = lane >> 4;
    const int eb   = tid >> 2, ejg = tid & 3;

    // load carry state
    {
        const size_t so = (size_t)dir * (64 * 512) + (size_t)eb * 512 + hc0 + ejg * 4;
        v4f hv = *(const v4f*)(hstate + so);
        v4f cv = *(const v4f*)(cstate + so);
        #pragma unroll
        for (int jj = 0; jj < 4; ++jj) { hS[eb][ejg * 4 + jj] = hv[jj]; cS[eb][ejg * 4 + jj] = cv[jj]; }
        if (tid < 64) lenS[tid] = lengths[tid];
    }

    const unsigned short* Wd = Wcat + (size_t)dir * (2048 * 1024);
    const int rowA0 = 32 * wm + l15, rowA1 = rowA0 + 16;
    const int n0 = (2 * wn + 0) * 512 + hc0 + l15;
    const int n1 = (2 * wn + 1) * 512 + hc0 + l15;
    const unsigned short* pB0 = Wd + (size_t)n0 * 1024 + kq * 8;
    const unsigned short* pB1 = Wd + (size_t)n1 * 1024 + kq * 8;

    // Whh fragments in registers (K = 512..1023)
    v8bf whB0[16], whB1[16];
    #pragma unroll
    for (int ks = 0; ks < 16; ++ks) {
        whB0[ks] = ldfrag(pB0 + (16 + ks) * 32);
        whB1[ks] = ldfrag(pB1 + (16 + ks) * 32);
    }

    const unsigned short* lA0 = hA + rowA0 * 512;
    const unsigned short* lA1 = hA + rowA1 * 512;
    const int swA0 = (rowA0 & 7) << 3, swA1 = (rowA1 & 7) << 3;

    unsigned char* recD = recb + (size_t)dir * 262144;   // 2 phases x 131072

    __syncthreads();

    for (int sl = 0; sl < TC; ++sl) {
        const int s = s0 + sl;
        const int t = dir ? (511 - s) : s;
        const unsigned want = (unsigned)s;

        // gx prefetch (bf16, 8 VGPRs) — plain loads, compiler-managed waits
        v2u gw0, gw1, gw2, gw3;
        {
            const unsigned short* g = gxb_rd + ((size_t)(dir * TC + sl) * 64 + eb) * 2048 + hc0 + ejg * 4;
            gw0 = *(const v2u*)(g);
            gw1 = *(const v2u*)(g + 512);
            gw2 = *(const v2u*)(g + 1024);
            gw3 = *(const v2u*)(g + 1536);
        }

        // poll stamped records for step s in batches of 8 (HARD LIMIT 8 live);
        // retries are wave-uniform bulk reloads (pattern (a) body).
        unsigned char* rp = recD + (size_t)(s & 1) * 131072;
        #pragma unroll
        for (int grp = 0; grp < 4; ++grp) {
            v4u r[8];
            #pragma unroll
            for (int i = 0; i < 8; ++i)
                r[i] = ld_co16(rp + (size_t)((grp * 8 + i) * 256 + tid) * 16);
            asm volatile("s_waitcnt vmcnt(0)" ::: "memory");
            __builtin_amdgcn_sched_barrier(0);      // rule #18 fence
            unsigned stale = 0u;
            #pragma unroll
            for (int i = 0; i < 8; ++i) {
                int idx = (grp * 8 + i) * 256 + tid;
                if (r[i][3] == want) {
                    int b = idx >> 7, j4 = idx & 127;
                    v2u hv = { r[i][0], r[i][1] };
                    *(v2u*)&hA[b * 512 + ((j4 * 4) ^ ((b & 7) << 3))] = hv;
                } else {
                    stale |= (1u << i);
                }
            }
            while (__any(stale != 0u)) {            // wave-uniform
                v4u q[8];
                #pragma unroll
                for (int i = 0; i < 8; ++i)         // UNCONDITIONAL reload
                    q[i] = ld_co16(rp + (size_t)((grp * 8 + i) * 256 + tid) * 16);
                asm volatile("s_waitcnt vmcnt(0)" ::: "memory");
                __builtin_amdgcn_sched_barrier(0);  // rule #18 fence
                #pragma unroll
                for (int i = 0; i < 8; ++i) {
                    if ((stale & (1u << i)) && q[i][3] == want) {
                        int idx = (grp * 8 + i) * 256 + tid;
                        int b = idx >> 7, j4 = idx & 127;
                        v2u hv = { q[i][0], q[i][1] };
                        *(v2u*)&hA[b * 512 + ((j4 * 4) ^ ((b & 7) << 3))] = hv;
                        stale &= ~(1u << i);
                    }
                }
            }
        }
        __syncthreads();

        // h-GEMM: K = 512, A from LDS, B from registers
        v4f a00 = {0,0,0,0}, a01 = {0,0,0,0}, a10 = {0,0,0,0}, a11 = {0,0,0,0};
        #pragma unroll
        for (int ks = 0; ks < 16; ++ks) {
            v8bf fa0 = *(const v8bf*)&lA0[(kq * 8 + ks * 32) ^ swA0];
            v8bf fa1 = *(const v8bf*)&lA1[(kq * 8 + ks * 32) ^ swA1];
            a00 = __builtin_amdgcn_mfma_f32_16x16x32_bf16(fa0, whB0[ks], a00, 0, 0, 0);
            a01 = __builtin_amdgcn_mfma_f32_16x16x32_bf16(fa0, whB1[ks], a01, 0, 0, 0);
            a10 = __builtin_amdgcn_mfma_f32_16x16x32_bf16(fa1, whB0[ks], a10, 0, 0, 0);
            a11 = __builtin_amdgcn_mfma_f32_16x16x32_bf16(fa1, whB1[ks], a11, 0, 0, 0);
        }

        // gates -> LDS. C/D: col = lane&15, row = (lane>>4)*4 + reg.
        {
            int c0 = 32 * wn + l15;
            int rr = 32 * wm + kq * 4;
            #pragma unroll
            for (int q = 0; q < 4; ++q) {
                gLds[rr + q][c0     ] = a00[q];
                gLds[rr + q][c0 + 16] = a01[q];
                gLds[rr + 16 + q][c0     ] = a10[q];
                gLds[rr + 16 + q][c0 + 16] = a11[q];
            }
        }
        __syncthreads();

        // elementwise LSTM: thread (b = tid>>2, cols hc0 + (tid&3)*4 + 0..3)
        {
            const int b = eb, jg = ejg;
            const int msk = (t < lenS[b]);
            float gxi[4], gxf[4], gxg[4], gxo[4];
            bf2x(gw0[0], gxi[0], gxi[1]); bf2x(gw0[1], gxi[2], gxi[3]);
            bf2x(gw1[0], gxf[0], gxf[1]); bf2x(gw1[1], gxf[2], gxf[3]);
            bf2x(gw2[0], gxg[0], gxg[1]); bf2x(gw2[1], gxg[2], gxg[3]);
            bf2x(gw3[0], gxo[0], gxo[1]); bf2x(gw3[1], gxo[2], gxo[3]);
            float hn[4], cn[4];
            #pragma unroll
            for (int jj = 0; jj < 4; ++jj) {
                int j = jg * 4 + jj;
                float gi = gLds[b][j]      + gxi[jj];
                float gf = gLds[b][16 + j] + gxf[jj];
                float gg = gLds[b][32 + j] + gxg[jj];
                float go = gLds[b][48 + j] + gxo[jj];
                float i_ = fsig(gi), f_ = fsig(gf), o_ = fsig(go), g_ = ftanh(gg);
                float c_old = cS[b][j], h_old = hS[b][j];
                float c_new = fmaf(f_, c_old, i_ * g_);
                float h_new = o_ * ftanh(c_new);
                if (!msk) { c_new = c_old; h_new = h_old; }
                cS[b][j] = c_new;
                hS[b][j] = h_new;
                hn[jj] = h_new; cn[jj] = c_new;
            }
            // publish first (single fire-and-forget coherent 16B record)
            if (s < 511) {
                unsigned short q0 = f2bf(hn[0]), q1 = f2bf(hn[1]), q2 = f2bf(hn[2]), q3 = f2bf(hn[3]);
                v4u pk = { (unsigned)q0 | ((unsigned)q1 << 16),
                           (unsigned)q2 | ((unsigned)q3 << 16),
                           0u, (unsigned)(s + 1) };
                int idxp = b * 128 + (wg & 31) * 4 + jg;
                unsigned char* dst = recD + (size_t)((s + 1) & 1) * 131072 + (size_t)idxp * 16;
                asm volatile("global_store_dwordx4 %0, %1, off sc0 sc1" :: "v"(dst), "v"(pk) : "memory");
            }
            v4f ov = {hn[0], hn[1], hn[2], hn[3]};
            *(v4f*)&out[((size_t)b * 512 + t) * 1024 + (size_t)dir * 512 + hc0 + jg * 4] = ov;
            if (s == 511) {
                v4f cv2 = {cn[0], cn[1], cn[2], cn[3]};
                *(v4f*)&out[OUT_HT + (size_t)b * 1024 + dir * 512 + hc0 + jg * 4] = ov;
                *(v4f*)&out[OUT_CT + (size_t)b * 1024 + dir * 512 + hc0 + jg * 4] = cv2;
            }
        }
        __syncthreads();   // protect gLds/hA reuse next step
    }

    // save carry state
    {
        float hv[4], cv[4];
        #pragma unroll
        for (int jj = 0; jj < 4; ++jj) { hv[jj] = hS[eb][ejg * 4 + jj]; cv[jj] = cS[eb][ejg * 4 + jj]; }
        const size_t so = (size_t)dir * (64 * 512) + (size_t)eb * 512 + hc0 + ejg * 4;
        *(v4f*)(hstate + so) = *(v4f*)hv;
        *(v4f*)(cstate + so) = *(v4f*)cv;
    }
}

// --------------------------- launcher --------------------------------------

extern "C" void kernel_launch(void* const* d_in, const int* in_sizes, int n_in,
                              void* d_out, int out_size, void* d_ws, size_t ws_size,
                              hipStream_t stream) {
    (void)in_sizes; (void)n_in; (void)out_size; (void)ws_size;

    const int*   inputs  = (const int*)d_in[0];
    const int*   lengths = (const int*)d_in[1];
    const float* table   = (const float*)d_in[2];
    const float* Wih_f   = (const float*)d_in[3];
    const float* Whh_f   = (const float*)d_in[4];
    const float* bih_f   = (const float*)d_in[5];
    const float* bhh_f   = (const float*)d_in[6];
    const float* Wih_b   = (const float*)d_in[7];
    const float* Whh_b   = (const float*)d_in[8];
    const float* bih_b   = (const float*)d_in[9];
    const float* bhh_b   = (const float*)d_in[10];
    float* out = (float*)d_out;

    char* w = (char*)d_ws;
    unsigned short* Wcat   = (unsigned short*)(w + WS_WCAT);
    unsigned short* gxb0   = (unsigned short*)(w + WS_GX0);
    unsigned short* gxb1   = (unsigned short*)(w + WS_GX1);
    unsigned char*  recb   = (unsigned char*)(w + WS_REC);
    float*          hstate = (float*)(w + WS_HST);
    float*          cstate = (float*)(w + WS_CST);
    unsigned short* gxb[2] = { gxb0, gxb1 };

    k_weights<<<4096, 256, 0, stream>>>(Wih_f, Whh_f, Wih_b, Whh_b, Wcat);
    k_zero<<<256, 256, 0, stream>>>(recb, hstate, cstate);
    k_mask<<<128, 256, 0, stream>>>(lengths, out + OUT_MSK);

    // prologue: gx for chunk 0 into buf0
    k_gx<<<256, 256, 0, stream>>>(inputs, table, Wcat,
                                  bih_f, bhh_f, bih_b, bhh_b, gxb0, 0);

    for (int ch = 0; ch < NCH; ++ch) {
        const int next_s0 = (ch < NCH - 1) ? (ch + 1) * TC : -1;
        fused<<<128, 256, 0, stream>>>(Wcat, recb, gxb[ch & 1], gxb[(ch + 1) & 1],
                                       inputs, table,
                                       bih_f, bhh_f, bih_b, bhh_b,
                                       lengths, out, hstate, cstate,
                                       ch * TC, next_s0);
    }
}

// Round 19
// 3497.608 us; speedup vs baseline: 1.0703x; 1.0703x over previous
//
#include <hip/hip_runtime.h>

// ---------------------------------------------------------------------------
// TranslatorEncoderRNN: bidirectional masked LSTM encoder.
// B=64, T=512, E=512, H=512 (per dir), V=32000, PAD=0.
// Outputs (flat): output (B,T,1024) f32 | ht (B,1024) | ct (B,1024) | mask (B,T)
//
// R19 = R16 verbatim (proven green, 3498us — session best). R18's gx
// de-burst regressed (rotation broke cross-block L2 sharing of Wcat tiles).
// FINAL STRUCTURE:
//   prologue k_gx (chunk 0) -> 16x fused{recurrence(ch) || gx(ch+1)}.
//   Recurrence: 64 persistent WGs, Whh in regs, h exchanged via stamped
//   16B coherent records, 4x8-load poll groups, wave-uniform bulk retry.
//   gx: 64 blocks (one per (d,sl)), token rows gathered once to regs,
//   16x synchronized LDS-staged W-tiles (constructive L2 sharing).
// CONSTRAINTS (empirical R3-R18):
//   (a) unconditional batch of <=8 ld_co16 + vmcnt(0) + sched_barrier(0); or
//   (b) fused {load; waitcnt} single asm block.
//   <=8 asm-load dest regs live at ANY point (R17: 16 live -> 1.1118 spill).
//   NEVER asm loads under divergent per-lane branches (NaN signature).
//   gx: >=64 parallel blocks, LDS-staged B, SYNCHRONIZED tile order
//     (R13 8-wave, R15 16-block, R18 rotation all regressed).
//   lstm_recur stays 256 thr (512-thr remap failed unexplained, R12).
// ---------------------------------------------------------------------------

#define Bn 64
#define Tn 512
#define NWG 64             // recurrence blocks (32 per direction)
#define TC 32              // chunk length
#define NCH 16             // chunks

#define OUT_HT  33554432u  // B*T*2H
#define OUT_CT  33619968u
#define OUT_MSK 33685504u

// ws layout (bytes) — total 42,991,616 (proven green R14/R16)
#define WS_WCAT 0ull           // Wcat bf16 [2][2048][1024]   =  8388608
#define WS_GX0  8388608ull     // gxb buf0 bf16 [2][32][64][2048] = 16777216
#define WS_GX1  25165824ull    // gxb buf1 (same)             = 16777216
#define WS_REC  41943040ull    // rec [2][2][8192]x16B        =   524288
#define WS_HST  42467328ull    // hstate f32 [2][64][512]     =   262144
#define WS_CST  42729472ull    // cstate f32 [2][64][512]     =   262144

typedef __bf16 v8bf __attribute__((ext_vector_type(8)));
typedef float  v4f  __attribute__((ext_vector_type(4)));
typedef unsigned v4u __attribute__((ext_vector_type(4)));
typedef unsigned v2u __attribute__((ext_vector_type(2)));

__device__ __forceinline__ unsigned short f2bf(float f) {
    unsigned u = __float_as_uint(f);
    u = (u + 0x7FFFu + ((u >> 16) & 1u)) >> 16;   // round-to-nearest-even
    return (unsigned short)u;
}

__device__ __forceinline__ void bf2x(unsigned u, float& lo, float& hi) {
    lo = __uint_as_float(u << 16);
    hi = __uint_as_float(u & 0xffff0000u);
}

__device__ __forceinline__ v8bf ldfrag(const unsigned short* p) {
    return *reinterpret_cast<const v8bf*>(p);
}

// coherent 16B load, ASYNC issue — pattern (a) only
__device__ __forceinline__ v4u ld_co16(const void* p) {
    v4u r;
    asm volatile("global_load_dwordx4 %0, %1, off sc0 sc1" : "=v"(r) : "v"(p));
    return r;
}

__device__ __forceinline__ float fsig(float x) {
    return 1.0f / (1.0f + __expf(-x));
}
__device__ __forceinline__ float ftanh(float x) {
    x = fminf(fmaxf(x, -15.0f), 15.0f);
    float e = __expf(2.0f * x);
    return (e - 1.0f) / (e + 1.0f);
}

// --------------------------- prep kernels ----------------------------------

__global__ void k_weights(const float* __restrict__ Wih_f, const float* __restrict__ Whh_f,
                          const float* __restrict__ Wih_b, const float* __restrict__ Whh_b,
                          unsigned short* __restrict__ Wcat) {
    int idx = blockIdx.x * 256 + threadIdx.x;       // one per 4 elements
    if (idx >= 2 * 2048 * 256) return;
    int k4 = idx & 255;
    int n  = (idx >> 8) & 2047;
    int d  = idx >> 19;
    int k  = k4 * 4;
    const float* src;
    if (k < 512) src = (d ? Wih_b : Wih_f) + (size_t)n * 512 + k;
    else         src = (d ? Whh_b : Whh_f) + (size_t)n * 512 + (k - 512);
    float4 v = *(const float4*)src;
    unsigned short o[4] = { f2bf(v.x), f2bf(v.y), f2bf(v.z), f2bf(v.w) };
    *(ushort4*)(Wcat + (size_t)idx * 4) = *(const ushort4*)o;
}

// zero records (stamps) and h/c carry state
__global__ void k_zero(unsigned char* __restrict__ recb,
                       float* __restrict__ hstate, float* __restrict__ cstate) {
    int i = blockIdx.x * 256 + threadIdx.x;         // grid 256x256 = 65536
    if (i < 32768) { v4u z = {0,0,0,0}; ((v4u*)recb)[i] = z; }
    if (i < 65536) { hstate[i] = 0.0f; cstate[i] = 0.0f; }
}

__global__ void k_mask(const int* __restrict__ lengths, float* __restrict__ mask_out) {
    int i = blockIdx.x * 256 + threadIdx.x;
    if (i >= Bn * Tn) return;
    int b = i >> 9, t = i & 511;
    mask_out[i] = (t < lengths[b]) ? 1.0f : 0.0f;
}

// --------------------------- embedding gather to regs -----------------------

__device__ __forceinline__ void gather_af(
    const int* __restrict__ inputs, const float* __restrict__ table,
    int d, int s, int ab, v8bf* af, int kq)
{
    const int t   = d ? (511 - s) : s;
    const int tok = inputs[ab * 512 + t];
    if (tok != 0) {
        const float* tr = table + (size_t)tok * 512 + kq * 8;
        #pragma unroll
        for (int ks = 0; ks < 16; ++ks) {
            float4 v0 = *(const float4*)(tr + ks * 32);
            float4 v1 = *(const float4*)(tr + ks * 32 + 4);
            unsigned short o[8] = { f2bf(v0.x), f2bf(v0.y), f2bf(v0.z), f2bf(v0.w),
                                    f2bf(v1.x), f2bf(v1.y), f2bf(v1.z), f2bf(v1.w) };
            af[ks] = *(const v8bf*)o;
        }
    } else {
        v4u z = {0u, 0u, 0u, 0u};
        #pragma unroll
        for (int ks = 0; ks < 16; ++ks) af[ks] = __builtin_bit_cast(v8bf, z);
    }
}

// --------------------------- standalone k_gx (prologue, chunk 0) ------------
// Green R11 form: 256 blocks (d,slg,nt), LDS-staged B tile, 4 slots.

__global__ __launch_bounds__(256) void k_gx(
    const int* __restrict__ inputs,
    const float* __restrict__ table,
    const unsigned short* __restrict__ Wcat,
    const float* __restrict__ bih_f, const float* __restrict__ bhh_f,
    const float* __restrict__ bih_b, const float* __restrict__ bhh_b,
    unsigned short* __restrict__ gxw, int s0)
{
    __shared__ unsigned short Bs[128 * 512];        // 128 KB
    const int bi   = blockIdx.x;                    // grid 256
    const int nt   = bi >> 4;                       // stride-16 -> same XCD per (d,slg)
    const int d    = (bi >> 3) & 1;
    const int slg  = bi & 7;
    const int n0   = nt * 128;
    const int tid  = threadIdx.x;
    const int lane = tid & 63, wave = tid >> 6;
    const int l15  = lane & 15, kq = lane >> 4;

    const unsigned short* Wd = Wcat + (size_t)d * (2048 * 1024);

    #pragma unroll
    for (int i = 0; i < 32; ++i) {
        int w = i * 256 + tid;
        int r = w >> 6, c = w & 63;
        v4u tmp = *(const v4u*)(Wd + (size_t)(n0 + r) * 1024 + c * 8);
        *(v4u*)&Bs[r * 512 + ((c ^ (r & 7)) * 8)] = tmp;
    }

    const float* bih = d ? bih_b : bih_f;
    const float* bhh = d ? bhh_b : bhh_f;
    float bv[8];
    #pragma unroll
    for (int n2 = 0; n2 < 8; ++n2) {
        int n = n0 + n2 * 16 + l15;
        bv[n2] = bih[n] + bhh[n];
    }
    __syncthreads();

    const int ab   = wave * 16 + l15;
    const int brow = wave * 16 + kq * 4;

    #pragma unroll 1
    for (int q = 0; q < 4; ++q) {
        const int sl = slg * 4 + q;
        v8bf af[16];
        gather_af(inputs, table, d, s0 + sl, ab, af, kq);

        unsigned short* gbase = gxw + ((size_t)(d * TC + sl) * 64) * 2048;
        #pragma unroll
        for (int n2 = 0; n2 < 8; ++n2) {
            v4f acc = {0, 0, 0, 0};
            const int rb = n2 * 16 + l15;
            const unsigned short* bbp = Bs + rb * 512;
            const int sw = rb & 7;
            #pragma unroll
            for (int ks = 0; ks < 16; ++ks) {
                v8bf bf = *(const v8bf*)&bbp[((ks * 4 + kq) ^ sw) * 8];
                acc = __builtin_amdgcn_mfma_f32_16x16x32_bf16(af[ks], bf, acc, 0, 0, 0);
            }
            const int n = n0 + n2 * 16 + l15;
            #pragma unroll
            for (int qq = 0; qq < 4; ++qq)
                gbase[(size_t)(brow + qq) * 2048 + n] = f2bf(acc[qq] + bv[n2]);
        }
    }
}

// --------------------------- fused kernel -----------------------------------
// blocks 0..63: recurrence chunk ch (reads gxb_rd).
// blocks 64..127: gx for chunk ch+1, one block per (d,sl): gather the slot's
// 64 token rows ONCE into regs, then 16x {stage W-tile in LDS -> 8 MFMAs}.

__global__ __launch_bounds__(256, 1) void fused(
    const unsigned short* __restrict__ Wcat,
    unsigned char* __restrict__ recb,           // [2][2][8192] x 16B
    const unsigned short* __restrict__ gxb_rd,  // chunk ch
    unsigned short* __restrict__ gxb_wr,        // chunk ch+1
    const int* __restrict__ inputs,
    const float* __restrict__ table,
    const float* __restrict__ bih_f, const float* __restrict__ bhh_f,
    const float* __restrict__ bih_b, const float* __restrict__ bhh_b,
    const int* __restrict__ lengths,
    float* __restrict__ out,
    float* __restrict__ hstate,
    float* __restrict__ cstate,
    int s0, int next_s0)
{
    __shared__ __align__(16) unsigned char smem[131072];

    const int tid = threadIdx.x;

    if (blockIdx.x >= 64) {
        // ------------------ gx path (chunk ch+1) ------------------
        if (next_s0 < 0) return;
        const int gxi = blockIdx.x - 64;            // [0,64)
        const int d   = gxi >> 5;
        const int sl  = gxi & 31;
        const int lane = tid & 63, wave = tid >> 6;
        const int l15  = lane & 15, kq = lane >> 4;
        const int ab   = wave * 16 + l15;
        const int brow = wave * 16 + kq * 4;
        unsigned short* Bs = (unsigned short*)smem;
        const unsigned short* Wd = Wcat + (size_t)d * (2048 * 1024);
        const float* bih = d ? bih_b : bih_f;
        const float* bhh = d ? bhh_b : bhh_f;

        // gather this slot's 64 token rows ONCE (64 VGPRs)
        v8bf af[16];
        gather_af(inputs, table, d, next_s0 + sl, ab, af, kq);

        unsigned short* gbase = gxb_wr + ((size_t)(d * TC + sl) * 64) * 2048;

        #pragma unroll 1
        for (int nt = 0; nt < 16; ++nt) {
            const int n0 = nt * 128;
            // stage B tile (rows n0..n0+127, k 0..511) swizzled
            #pragma unroll
            for (int i = 0; i < 32; ++i) {
                int w2 = i * 256 + tid;
                int r = w2 >> 6, c = w2 & 63;
                v4u tmp = *(const v4u*)(Wd + (size_t)(n0 + r) * 1024 + c * 8);
                *(v4u*)&Bs[r * 512 + ((c ^ (r & 7)) * 8)] = tmp;
            }
            __syncthreads();

            #pragma unroll
            for (int n2 = 0; n2 < 8; ++n2) {
                v4f acc = {0, 0, 0, 0};
                const int rb = n2 * 16 + l15;
                const unsigned short* bbp = Bs + rb * 512;
                const int sw = rb & 7;
                #pragma unroll
                for (int ks = 0; ks < 16; ++ks) {
                    v8bf bf = *(const v8bf*)&bbp[((ks * 4 + kq) ^ sw) * 8];
                    acc = __builtin_amdgcn_mfma_f32_16x16x32_bf16(af[ks], bf, acc, 0, 0, 0);
                }
                const int n = n0 + n2 * 16 + l15;
                const float bv = bih[n] + bhh[n];
                #pragma unroll
                for (int qq = 0; qq < 4; ++qq)
                    gbase[(size_t)(brow + qq) * 2048 + n] = f2bf(acc[qq] + bv);
            }
            __syncthreads();                        // Bs reuse next nt
        }
        return;
    }

    // ------------------ recurrence path (chunk ch) — R11 body ------------------
    unsigned short* hA = (unsigned short*)smem;             // 65536 B
    float (*gLds)[65]  = reinterpret_cast<float(*)[65]>(smem + 65536);   // 16640 B
    float (*hS)[17]    = reinterpret_cast<float(*)[17]>(smem + 82176);   //  4352 B
    float (*cS)[17]    = reinterpret_cast<float(*)[17]>(smem + 86528);   //  4352 B
    int* lenS          = reinterpret_cast<int*>(smem + 90880);           //   256 B

    const int wg   = blockIdx.x;
    const int dir  = wg >> 5;
    const int hc0  = (wg & 31) * 16;
    const int lane = tid & 63;
    const int wave = tid >> 6;
    const int wm   = wave >> 1, wn = wave & 1;
    const int l15  = lane & 15, kq = lane >> 4;
    const int eb   = tid >> 2, ejg = tid & 3;

    // load carry state
    {
        const size_t so = (size_t)dir * (64 * 512) + (size_t)eb * 512 + hc0 + ejg * 4;
        v4f hv = *(const v4f*)(hstate + so);
        v4f cv = *(const v4f*)(cstate + so);
        #pragma unroll
        for (int jj = 0; jj < 4; ++jj) { hS[eb][ejg * 4 + jj] = hv[jj]; cS[eb][ejg * 4 + jj] = cv[jj]; }
        if (tid < 64) lenS[tid] = lengths[tid];
    }

    const unsigned short* Wd = Wcat + (size_t)dir * (2048 * 1024);
    const int rowA0 = 32 * wm + l15, rowA1 = rowA0 + 16;
    const int n0 = (2 * wn + 0) * 512 + hc0 + l15;
    const int n1 = (2 * wn + 1) * 512 + hc0 + l15;
    const unsigned short* pB0 = Wd + (size_t)n0 * 1024 + kq * 8;
    const unsigned short* pB1 = Wd + (size_t)n1 * 1024 + kq * 8;

    // Whh fragments in registers (K = 512..1023)
    v8bf whB0[16], whB1[16];
    #pragma unroll
    for (int ks = 0; ks < 16; ++ks) {
        whB0[ks] = ldfrag(pB0 + (16 + ks) * 32);
        whB1[ks] = ldfrag(pB1 + (16 + ks) * 32);
    }

    const unsigned short* lA0 = hA + rowA0 * 512;
    const unsigned short* lA1 = hA + rowA1 * 512;
    const int swA0 = (rowA0 & 7) << 3, swA1 = (rowA1 & 7) << 3;

    unsigned char* recD = recb + (size_t)dir * 262144;   // 2 phases x 131072

    __syncthreads();

    for (int sl = 0; sl < TC; ++sl) {
        const int s = s0 + sl;
        const int t = dir ? (511 - s) : s;
        const unsigned want = (unsigned)s;

        // gx prefetch (bf16, 8 VGPRs) — plain loads, compiler-managed waits
        v2u gw0, gw1, gw2, gw3;
        {
            const unsigned short* g = gxb_rd + ((size_t)(dir * TC + sl) * 64 + eb) * 2048 + hc0 + ejg * 4;
            gw0 = *(const v2u*)(g);
            gw1 = *(const v2u*)(g + 512);
            gw2 = *(const v2u*)(g + 1024);
            gw3 = *(const v2u*)(g + 1536);
        }

        // poll stamped records for step s in batches of 8 (HARD LIMIT 8 live);
        // retries are wave-uniform bulk reloads (pattern (a) body).
        unsigned char* rp = recD + (size_t)(s & 1) * 131072;
        #pragma unroll
        for (int grp = 0; grp < 4; ++grp) {
            v4u r[8];
            #pragma unroll
            for (int i = 0; i < 8; ++i)
                r[i] = ld_co16(rp + (size_t)((grp * 8 + i) * 256 + tid) * 16);
            asm volatile("s_waitcnt vmcnt(0)" ::: "memory");
            __builtin_amdgcn_sched_barrier(0);      // rule #18 fence
            unsigned stale = 0u;
            #pragma unroll
            for (int i = 0; i < 8; ++i) {
                int idx = (grp * 8 + i) * 256 + tid;
                if (r[i][3] == want) {
                    int b = idx >> 7, j4 = idx & 127;
                    v2u hv = { r[i][0], r[i][1] };
                    *(v2u*)&hA[b * 512 + ((j4 * 4) ^ ((b & 7) << 3))] = hv;
                } else {
                    stale |= (1u << i);
                }
            }
            while (__any(stale != 0u)) {            // wave-uniform
                v4u q[8];
                #pragma unroll
                for (int i = 0; i < 8; ++i)         // UNCONDITIONAL reload
                    q[i] = ld_co16(rp + (size_t)((grp * 8 + i) * 256 + tid) * 16);
                asm volatile("s_waitcnt vmcnt(0)" ::: "memory");
                __builtin_amdgcn_sched_barrier(0);  // rule #18 fence
                #pragma unroll
                for (int i = 0; i < 8; ++i) {
                    if ((stale & (1u << i)) && q[i][3] == want) {
                        int idx = (grp * 8 + i) * 256 + tid;
                        int b = idx >> 7, j4 = idx & 127;
                        v2u hv = { q[i][0], q[i][1] };
                        *(v2u*)&hA[b * 512 + ((j4 * 4) ^ ((b & 7) << 3))] = hv;
                        stale &= ~(1u << i);
                    }
                }
            }
        }
        __syncthreads();

        // h-GEMM: K = 512, A from LDS, B from registers
        v4f a00 = {0,0,0,0}, a01 = {0,0,0,0}, a10 = {0,0,0,0}, a11 = {0,0,0,0};
        #pragma unroll
        for (int ks = 0; ks < 16; ++ks) {
            v8bf fa0 = *(const v8bf*)&lA0[(kq * 8 + ks * 32) ^ swA0];
            v8bf fa1 = *(const v8bf*)&lA1[(kq * 8 + ks * 32) ^ swA1];
            a00 = __builtin_amdgcn_mfma_f32_16x16x32_bf16(fa0, whB0[ks], a00, 0, 0, 0);
            a01 = __builtin_amdgcn_mfma_f32_16x16x32_bf16(fa0, whB1[ks], a01, 0, 0, 0);
            a10 = __builtin_amdgcn_mfma_f32_16x16x32_bf16(fa1, whB0[ks], a10, 0, 0, 0);
            a11 = __builtin_amdgcn_mfma_f32_16x16x32_bf16(fa1, whB1[ks], a11, 0, 0, 0);
        }

        // gates -> LDS. C/D: col = lane&15, row = (lane>>4)*4 + reg.
        {
            int c0 = 32 * wn + l15;
            int rr = 32 * wm + kq * 4;
            #pragma unroll
            for (int q = 0; q < 4; ++q) {
                gLds[rr + q][c0     ] = a00[q];
                gLds[rr + q][c0 + 16] = a01[q];
                gLds[rr + 16 + q][c0     ] = a10[q];
                gLds[rr + 16 + q][c0 + 16] = a11[q];
            }
        }
        __syncthreads();

        // elementwise LSTM: thread (b = tid>>2, cols hc0 + (tid&3)*4 + 0..3)
        {
            const int b = eb, jg = ejg;
            const int msk = (t < lenS[b]);
            float gxi[4], gxf[4], gxg[4], gxo[4];
            bf2x(gw0[0], gxi[0], gxi[1]); bf2x(gw0[1], gxi[2], gxi[3]);
            bf2x(gw1[0], gxf[0], gxf[1]); bf2x(gw1[1], gxf[2], gxf[3]);
            bf2x(gw2[0], gxg[0], gxg[1]); bf2x(gw2[1], gxg[2], gxg[3]);
            bf2x(gw3[0], gxo[0], gxo[1]); bf2x(gw3[1], gxo[2], gxo[3]);
            float hn[4], cn[4];
            #pragma unroll
            for (int jj = 0; jj < 4; ++jj) {
                int j = jg * 4 + jj;
                float gi = gLds[b][j]      + gxi[jj];
                float gf = gLds[b][16 + j] + gxf[jj];
                float gg = gLds[b][32 + j] + gxg[jj];
                float go = gLds[b][48 + j] + gxo[jj];
                float i_ = fsig(gi), f_ = fsig(gf), o_ = fsig(go), g_ = ftanh(gg);
                float c_old = cS[b][j], h_old = hS[b][j];
                float c_new = fmaf(f_, c_old, i_ * g_);
                float h_new = o_ * ftanh(c_new);
                if (!msk) { c_new = c_old; h_new = h_old; }
                cS[b][j] = c_new;
                hS[b][j] = h_new;
                hn[jj] = h_new; cn[jj] = c_new;
            }
            // publish first (single fire-and-forget coherent 16B record)
            if (s < 511) {
                unsigned short q0 = f2bf(hn[0]), q1 = f2bf(hn[1]), q2 = f2bf(hn[2]), q3 = f2bf(hn[3]);
                v4u pk = { (unsigned)q0 | ((unsigned)q1 << 16),
                           (unsigned)q2 | ((unsigned)q3 << 16),
                           0u, (unsigned)(s + 1) };
                int idxp = b * 128 + (wg & 31) * 4 + jg;
                unsigned char* dst = recD + (size_t)((s + 1) & 1) * 131072 + (size_t)idxp * 16;
                asm volatile("global_store_dwordx4 %0, %1, off sc0 sc1" :: "v"(dst), "v"(pk) : "memory");
            }
            v4f ov = {hn[0], hn[1], hn[2], hn[3]};
            *(v4f*)&out[((size_t)b * 512 + t) * 1024 + (size_t)dir * 512 + hc0 + jg * 4] = ov;
            if (s == 511) {
                v4f cv2 = {cn[0], cn[1], cn[2], cn[3]};
                *(v4f*)&out[OUT_HT + (size_t)b * 1024 + dir * 512 + hc0 + jg * 4] = ov;
                *(v4f*)&out[OUT_CT + (size_t)b * 1024 + dir * 512 + hc0 + jg * 4] = cv2;
            }
        }
        __syncthreads();   // protect gLds/hA reuse next step
    }

    // save carry state
    {
        float hv[4], cv[4];
        #pragma unroll
        for (int jj = 0; jj < 4; ++jj) { hv[jj] = hS[eb][ejg * 4 + jj]; cv[jj] = cS[eb][ejg * 4 + jj]; }
        const size_t so = (size_t)dir * (64 * 512) + (size_t)eb * 512 + hc0 + ejg * 4;
        *(v4f*)(hstate + so) = *(v4f*)hv;
        *(v4f*)(cstate + so) = *(v4f*)cv;
    }
}

// --------------------------- launcher --------------------------------------

extern "C" void kernel_launch(void* const* d_in, const int* in_sizes, int n_in,
                              void* d_out, int out_size, void* d_ws, size_t ws_size,
                              hipStream_t stream) {
    (void)in_sizes; (void)n_in; (void)out_size; (void)ws_size;

    const int*   inputs  = (const int*)d_in[0];
    const int*   lengths = (const int*)d_in[1];
    const float* table   = (const float*)d_in[2];
    const float* Wih_f   = (const float*)d_in[3];
    const float* Whh_f   = (const float*)d_in[4];
    const float* bih_f   = (const float*)d_in[5];
    const float* bhh_f   = (const float*)d_in[6];
    const float* Wih_b   = (const float*)d_in[7];
    const float* Whh_b   = (const float*)d_in[8];
    const float* bih_b   = (const float*)d_in[9];
    const float* bhh_b   = (const float*)d_in[10];
    float* out = (float*)d_out;

    char* w = (char*)d_ws;
    unsigned short* Wcat   = (unsigned short*)(w + WS_WCAT);
    unsigned short* gxb0   = (unsigned short*)(w + WS_GX0);
    unsigned short* gxb1   = (unsigned short*)(w + WS_GX1);
    unsigned char*  recb   = (unsigned char*)(w + WS_REC);
    float*          hstate = (float*)(w + WS_HST);
    float*          cstate = (float*)(w + WS_CST);
    unsigned short* gxb[2] = { gxb0, gxb1 };

    k_weights<<<4096, 256, 0, stream>>>(Wih_f, Whh_f, Wih_b, Whh_b, Wcat);
    k_zero<<<256, 256, 0, stream>>>(recb, hstate, cstate);
    k_mask<<<128, 256, 0, stream>>>(lengths, out + OUT_MSK);

    // prologue: gx for chunk 0 into buf0
    k_gx<<<256, 256, 0, stream>>>(inputs, table, Wcat,
                                  bih_f, bhh_f, bih_b, bhh_b, gxb0, 0);

    for (int ch = 0; ch < NCH; ++ch) {
        const int next_s0 = (ch < NCH - 1) ? (ch + 1) * TC : -1;
        fused<<<128, 256, 0, stream>>>(Wcat, recb, gxb[ch & 1], gxb[(ch + 1) & 1],
                                       inputs, table,
                                       bih_f, bhh_f, bih_b, bhh_b,
                                       lengths, out, hstate, cstate,
                                       ch * TC, next_s0);
    }
}